// Round 1
// baseline (503.018 us; speedup 1.0000x reference)
//
#include <hip/hip_runtime.h>
#include <hip/hip_bf16.h>
#include <math.h>

// ---------------------------------------------------------------------------
// EdgeAwareAttention: B=1, N=50000, D=128, H=8, d=16, E=800000
// Plan:
//  K1 gemm128      : Q = x@Wq.T, K = x@Wk.T, V = x@Wv.T   (f32, LDS-tiled)
//  K2 hist/scan/fill: CSR of edges keyed by src
//  K3 edge_attn    : per src-node online softmax over its edges, gather K/V[dst]
//  K4 gemm128      : Y = AGG@Wo.T + x  (residual fused)
//  K5 ln           : LayerNorm(Y)*gamma+beta -> d_out
// ---------------------------------------------------------------------------

#define TILE_R 32

__global__ __launch_bounds__(256) void gemm128_kernel(
    const float* __restrict__ X, const float* __restrict__ W,
    float* __restrict__ Out, const float* __restrict__ resid, int N) {
  // Out[n][j] = sum_k X[n][k] * W[j][k]  (+ resid[n][j])
  __shared__ float Wl[128][65];   // k-half staged: [j][k]  pitch 65 -> bank=(j+k)%32
  __shared__ float Xl[TILE_R][65];
  int t = threadIdx.x;
  int r0 = blockIdx.x * TILE_R;
  int lam = t & 31;   // col group: cols lam + 32*i
  int rg  = t >> 5;   // row group: rows rg*4 + j
  float acc[4][4] = {{0.f}};

  for (int ks = 0; ks < 128; ks += 64) {
    // stage W half: 128x64
#pragma unroll
    for (int i = 0; i < 32; i++) {
      int idx = i * 256 + t;
      int j = idx >> 6, k = idx & 63;
      Wl[j][k] = W[j * 128 + ks + k];
    }
    // stage X tile half: 32x64
#pragma unroll
    for (int i = 0; i < 8; i++) {
      int idx = i * 256 + t;
      int r = idx >> 6, k = idx & 63;
      int gr = r0 + r;
      Xl[r][k] = (gr < N) ? X[gr * 128 + ks + k] : 0.f;
    }
    __syncthreads();
#pragma unroll 4
    for (int k = 0; k < 64; k++) {
      float wv[4], xv[4];
#pragma unroll
      for (int i = 0; i < 4; i++) wv[i] = Wl[lam + 32 * i][k];
#pragma unroll
      for (int j = 0; j < 4; j++) xv[j] = Xl[rg * 4 + j][k];
#pragma unroll
      for (int j = 0; j < 4; j++)
#pragma unroll
        for (int i = 0; i < 4; i++) acc[j][i] += xv[j] * wv[i];
    }
    __syncthreads();
  }

#pragma unroll
  for (int j = 0; j < 4; j++) {
    int gr = r0 + rg * 4 + j;
    if (gr < N) {
#pragma unroll
      for (int i = 0; i < 4; i++) {
        int col = lam + 32 * i;
        float v = acc[j][i];
        if (resid) v += resid[gr * 128 + col];
        Out[gr * 128 + col] = v;
      }
    }
  }
}

__global__ void hist_kernel(const int* __restrict__ ei, int* __restrict__ cnt, int E) {
  int e = blockIdx.x * blockDim.x + threadIdx.x;
  if (e < E) atomicAdd(&cnt[ei[e]], 1);
}

__global__ __launch_bounds__(1024) void scan_kernel(
    const int* __restrict__ cnt, int* __restrict__ offs, int N) {
  __shared__ int sums[1024];
  int t = threadIdx.x;
  int chunk = (N + 1023) / 1024;
  int lo = t * chunk;
  int hi = min(lo + chunk, N);
  int s = 0;
  for (int i = lo; i < hi; i++) s += cnt[i];
  sums[t] = s;
  __syncthreads();
  for (int d = 1; d < 1024; d <<= 1) {
    int v = (t >= d) ? sums[t - d] : 0;
    __syncthreads();
    sums[t] += v;
    __syncthreads();
  }
  int base = (t == 0) ? 0 : sums[t - 1];
  for (int i = lo; i < hi; i++) { offs[i] = base; base += cnt[i]; }
  if (t == 0) offs[N] = sums[1023];
}

__global__ void fill_kernel(const int* __restrict__ ei, const int* __restrict__ offs,
                            int* __restrict__ cur, int* __restrict__ csr, int E) {
  int e = blockIdx.x * blockDim.x + threadIdx.x;
  if (e < E) {
    int s = ei[e];
    int pos = atomicAdd(&cur[s], 1);
    csr[offs[s] + pos] = e;
  }
}

__global__ __launch_bounds__(64) void edge_attn_kernel(
    const float* __restrict__ Q, const float* __restrict__ K, const float* __restrict__ V,
    const int* __restrict__ ei, const float* __restrict__ ew, const float* __restrict__ We,
    const int* __restrict__ offs, const int* __restrict__ csr,
    float* __restrict__ AGG, int N, int E) {
  int n = blockIdx.x;
  int l = threadIdx.x;              // lane: owns dims {2l, 2l+1}; head = l>>3
  int h = l >> 3;
  float2 q = *(const float2*)(Q + (size_t)n * 128 + 2 * l);
  float weh = We[h];
  int o0 = offs[n], o1 = offs[n + 1];
  float m = -INFINITY, denom = 0.f, ax = 0.f, ay = 0.f;
  for (int i = o0; i < o1; i++) {
    int e = csr[i];
    int dst = ei[E + e];
    float2 kk = *(const float2*)(K + (size_t)dst * 128 + 2 * l);
    float s = q.x * kk.x + q.y * kk.y;
    s += __shfl_xor(s, 1);
    s += __shfl_xor(s, 2);
    s += __shfl_xor(s, 4);          // per-head dot, all 8 lanes of the group hold it
    s = s * 0.25f + ew[e] * weh;
    float2 vv = *(const float2*)(V + (size_t)dst * 128 + 2 * l);
    float mn = fmaxf(m, s);
    float c = __expf(m - mn);       // exp(-inf)=0 on first iter
    float p = __expf(s - mn);
    denom = denom * c + p;
    ax = ax * c + p * vv.x;
    ay = ay * c + p * vv.y;
    m = mn;
  }
  float inv = (denom > 0.f) ? 1.0f / denom : 0.f;
  float2 o = make_float2(ax * inv, ay * inv);
  *(float2*)(AGG + (size_t)n * 128 + 2 * l) = o;
}

__global__ __launch_bounds__(256) void ln_kernel(
    const float* __restrict__ Y, const float* __restrict__ gamma,
    const float* __restrict__ beta, float* __restrict__ out, int N) {
  int wid = threadIdx.x >> 6, l = threadIdx.x & 63;
  int n = blockIdx.x * 4 + wid;
  if (n >= N) return;
  float2 y = *(const float2*)(Y + (size_t)n * 128 + 2 * l);
  float s = y.x + y.y;
  float s2 = y.x * y.x + y.y * y.y;
#pragma unroll
  for (int d = 1; d < 64; d <<= 1) {
    s += __shfl_xor(s, d);
    s2 += __shfl_xor(s2, d);
  }
  float mu = s * (1.f / 128.f);
  float var = s2 * (1.f / 128.f) - mu * mu;
  float r = rsqrtf(var + 1e-5f);
  float2 g = *(const float2*)(gamma + 2 * l);
  float2 b = *(const float2*)(beta + 2 * l);
  float2 o = make_float2((y.x - mu) * r * g.x + b.x, (y.y - mu) * r * g.y + b.y);
  *(float2*)(out + (size_t)n * 128 + 2 * l) = o;
}

extern "C" void kernel_launch(void* const* d_in, const int* in_sizes, int n_in,
                              void* d_out, int out_size, void* d_ws, size_t ws_size,
                              hipStream_t stream) {
  const float* x     = (const float*)d_in[0];
  const int*   ei    = (const int*)d_in[1];
  const float* ew    = (const float*)d_in[2];
  const float* Wq    = (const float*)d_in[3];
  const float* Wk    = (const float*)d_in[4];
  const float* Wv    = (const float*)d_in[5];
  const float* We    = (const float*)d_in[6];
  const float* Wo    = (const float*)d_in[7];
  const float* gamma = (const float*)d_in[8];
  const float* beta  = (const float*)d_in[9];

  int N = in_sizes[0] / 128;
  int E = in_sizes[1] / 2;

  char* ws = (char*)d_ws;
  float* Q   = (float*)ws; ws += (size_t)N * 128 * 4;
  float* Kb  = (float*)ws; ws += (size_t)N * 128 * 4;
  float* Vb  = (float*)ws; ws += (size_t)N * 128 * 4;
  float* AGG = (float*)ws; ws += (size_t)N * 128 * 4;
  int* cnt  = (int*)ws; ws += (size_t)(N) * 4;
  int* offs = (int*)ws; ws += (size_t)(N + 1) * 4;
  int* cur  = (int*)ws; ws += (size_t)(N) * 4;
  int* csr  = (int*)ws; ws += (size_t)E * 4;
  float* Y = Q;  // reuse Q buffer for pre-LN result

  hipMemsetAsync(cnt, 0, (size_t)N * 4, stream);
  hipMemsetAsync(cur, 0, (size_t)N * 4, stream);

  int gblocks = (N + TILE_R - 1) / TILE_R;
  gemm128_kernel<<<gblocks, 256, 0, stream>>>(x, Wq, Q, nullptr, N);
  gemm128_kernel<<<gblocks, 256, 0, stream>>>(x, Wk, Kb, nullptr, N);
  gemm128_kernel<<<gblocks, 256, 0, stream>>>(x, Wv, Vb, nullptr, N);

  int eblocks = (E + 255) / 256;
  hist_kernel<<<eblocks, 256, 0, stream>>>(ei, cnt, E);
  scan_kernel<<<1, 1024, 0, stream>>>(cnt, offs, N);
  fill_kernel<<<eblocks, 256, 0, stream>>>(ei, offs, cur, csr, E);

  edge_attn_kernel<<<N, 64, 0, stream>>>(Q, Kb, Vb, ei, ew, We, offs, csr, AGG, N, E);

  gemm128_kernel<<<gblocks, 256, 0, stream>>>(AGG, Wo, Y, x, N);

  ln_kernel<<<(N + 3) / 4, 256, 0, stream>>>(Y, gamma, beta, (float*)d_out, N);
}

// Round 2
// 323.933 us; speedup vs baseline: 1.5528x; 1.5528x over previous
//
#include <hip/hip_runtime.h>
#include <hip/hip_bf16.h>
#include <math.h>

// ---------------------------------------------------------------------------
// EdgeAwareAttention: B=1, N=50000, D=128, H=8, d=16, E=800000
//  cvt_x    : x f32 -> bf16 (padded, zero-fill)
//  cvt_w    : Wq,Wk,Wv,Wo f32 -> bf16
//  qkv      : MFMA bf16: Q(f32), K(bf16), V(bf16)
//  hist/scan/fill: CSR by src; fill writes dst/ew directly in CSR order
//  edge_attn: per-node online softmax, 4 independent chains (MLP), bf16 K/V
//  wo_ln    : MFMA Wo GEMM + residual + LayerNorm fused -> d_out
// ---------------------------------------------------------------------------

typedef __attribute__((ext_vector_type(8))) short short8;
typedef __attribute__((ext_vector_type(4))) float f32x4;

static __device__ __forceinline__ ushort f2bf(float f) {
  unsigned u = __float_as_uint(f);
  u += 0x7fff + ((u >> 16) & 1);          // RNE
  return (ushort)(u >> 16);
}
static __device__ __forceinline__ float bf2f(unsigned hi16) {
  return __uint_as_float(hi16 << 16);
}

__global__ void cvt_x_kernel(const float* __restrict__ x, ushort* __restrict__ xb,
                             int nvalid, int ntot) {
  int i = (blockIdx.x * 256 + threadIdx.x) * 4;
  if (i >= ntot) return;
  ushort4 o;
  if (i < nvalid) {                        // rows are multiples of 4: chunk fully valid
    float4 v = *(const float4*)(x + i);
    o = make_ushort4(f2bf(v.x), f2bf(v.y), f2bf(v.z), f2bf(v.w));
  } else {
    o = make_ushort4(0, 0, 0, 0);
  }
  *(ushort4*)(xb + i) = o;
}

__global__ void cvt_w_kernel(const float* __restrict__ Wq, const float* __restrict__ Wk,
                             const float* __restrict__ Wv, const float* __restrict__ Wo,
                             ushort* __restrict__ out) {
  int i = (blockIdx.x * 256 + threadIdx.x) * 4;
  if (i >= 4 * 16384) return;
  const float* src = (i < 16384) ? Wq : (i < 32768) ? Wk : (i < 49152) ? Wv : Wo;
  int off = i & 16383;
  float4 v = *(const float4*)(src + off);
  *(ushort4*)(out + i) = make_ushort4(f2bf(v.x), f2bf(v.y), f2bf(v.z), f2bf(v.w));
}

// Q/K/V fused MFMA GEMM. Block = 256 thr = 4 waves; wave computes 16 rows x 384 cols.
__global__ __launch_bounds__(256) void qkv_kernel(
    const ushort* __restrict__ xb, const ushort* __restrict__ Wb,   // Wb: [3][128][128]
    float* __restrict__ Qf, ushort* __restrict__ Kb, ushort* __restrict__ Vb, int N) {
  int w = threadIdx.x >> 6, l = threadIdx.x & 63;
  int n0 = blockIdx.x * 64 + w * 16;
  int lr = l & 15, lg = l >> 4;
  // A frags: X[n0+lr][32*ks + 8*lg + j]
  short8 a[4];
  const ushort* xrow = xb + (size_t)(n0 + lr) * 128 + 8 * lg;
#pragma unroll
  for (int ks = 0; ks < 4; ks++) a[ks] = *(const short8*)(xrow + 32 * ks);

#pragma unroll
  for (int m = 0; m < 3; m++) {
    const ushort* Wm = Wb + m * 16384;
#pragma unroll
    for (int ct = 0; ct < 8; ct++) {
      f32x4 acc = {0.f, 0.f, 0.f, 0.f};
      const ushort* wrow = Wm + (size_t)(ct * 16 + lr) * 128 + 8 * lg;
#pragma unroll
      for (int ks = 0; ks < 4; ks++) {
        short8 b = *(const short8*)(wrow + 32 * ks);
        acc = __builtin_amdgcn_mfma_f32_16x16x32_bf16(a[ks], b, acc, 0, 0, 0);
      }
      int c = ct * 16 + lr;
#pragma unroll
      for (int r = 0; r < 4; r++) {
        int row = n0 + 4 * lg + r;
        if (row < N) {
          if (m == 0)      Qf[(size_t)row * 128 + c] = acc[r];
          else if (m == 1) Kb[(size_t)row * 128 + c] = f2bf(acc[r]);
          else             Vb[(size_t)row * 128 + c] = f2bf(acc[r]);
        }
      }
    }
  }
}

__global__ void hist_kernel(const int* __restrict__ ei, int* __restrict__ cnt, int E) {
  int e = blockIdx.x * blockDim.x + threadIdx.x;
  if (e < E) atomicAdd(&cnt[ei[e]], 1);
}

__global__ __launch_bounds__(1024) void scan_kernel(
    const int* __restrict__ cnt, int* __restrict__ offs, int N) {
  __shared__ int sums[1024];
  int t = threadIdx.x;
  int chunk = (N + 1023) / 1024;
  int lo = t * chunk;
  int hi = min(lo + chunk, N);
  int s = 0;
  for (int i = lo; i < hi; i++) s += cnt[i];
  sums[t] = s;
  __syncthreads();
  for (int d = 1; d < 1024; d <<= 1) {
    int v = (t >= d) ? sums[t - d] : 0;
    __syncthreads();
    sums[t] += v;
    __syncthreads();
  }
  int base = (t == 0) ? 0 : sums[t - 1];
  for (int i = lo; i < hi; i++) { offs[i] = base; base += cnt[i]; }
  if (t == 0) offs[N] = sums[1023];
}

__global__ void fill_kernel(const int* __restrict__ ei, const float* __restrict__ ew,
                            const int* __restrict__ offs, int* __restrict__ cur,
                            int* __restrict__ dsts, float* __restrict__ ews, int E) {
  int e = blockIdx.x * blockDim.x + threadIdx.x;
  if (e < E) {
    int s = ei[e];
    int pos = offs[s] + atomicAdd(&cur[s], 1);
    dsts[pos] = ei[E + e];
    ews[pos]  = ew[e];
  }
}

// 4 nodes per block (1 wave each). Lane l owns dims {2l,2l+1}; head = l>>3.
// 4 independent online-softmax chains for memory-level parallelism.
__global__ __launch_bounds__(256) void edge_attn_kernel(
    const float* __restrict__ Q, const ushort* __restrict__ Kb, const ushort* __restrict__ Vb,
    const int* __restrict__ dsts, const float* __restrict__ ews,
    const float* __restrict__ We, const int* __restrict__ offs,
    ushort* __restrict__ AGGb, int N) {
  int wv = threadIdx.x >> 6, l = threadIdx.x & 63;
  int n = blockIdx.x * 4 + wv;
  if (n >= N) return;
  int h = l >> 3;
  float2 q = *(const float2*)(Q + (size_t)n * 128 + 2 * l);
  float weh = We[h];
  int o0 = offs[n], o1 = offs[n + 1];

  float m[4], de[4], ax[4], ay[4];
#pragma unroll
  for (int u = 0; u < 4; u++) { m[u] = -INFINITY; de[u] = 0.f; ax[u] = 0.f; ay[u] = 0.f; }

  int i = o0;
  int nfull = o0 + ((o1 - o0) & ~3);
  for (; i < nfull; i += 4) {
    int dst[4]; float w4[4];
#pragma unroll
    for (int u = 0; u < 4; u++) { dst[u] = dsts[i + u]; w4[u] = ews[i + u]; }
    unsigned kk[4], vv[4];
#pragma unroll
    for (int u = 0; u < 4; u++) kk[u] = *(const unsigned*)(Kb + (size_t)dst[u] * 128 + 2 * l);
#pragma unroll
    for (int u = 0; u < 4; u++) vv[u] = *(const unsigned*)(Vb + (size_t)dst[u] * 128 + 2 * l);
#pragma unroll
    for (int u = 0; u < 4; u++) {
      float kx = bf2f(kk[u] & 0xffffu), ky = bf2f(kk[u] >> 16);
      float s = q.x * kx + q.y * ky;
      s += __shfl_xor(s, 1);
      s += __shfl_xor(s, 2);
      s += __shfl_xor(s, 4);
      s = s * 0.25f + w4[u] * weh;
      float vx = bf2f(vv[u] & 0xffffu), vy = bf2f(vv[u] >> 16);
      float mn = fmaxf(m[u], s);
      float c = __expf(m[u] - mn);
      float p = __expf(s - mn);
      de[u] = de[u] * c + p;
      ax[u] = ax[u] * c + p * vx;
      ay[u] = ay[u] * c + p * vy;
      m[u] = mn;
    }
  }
  for (; i < o1; i++) {                    // tail -> chain 0
    int dst = dsts[i];
    unsigned kk = *(const unsigned*)(Kb + (size_t)dst * 128 + 2 * l);
    float s = q.x * bf2f(kk & 0xffffu) + q.y * bf2f(kk >> 16);
    s += __shfl_xor(s, 1);
    s += __shfl_xor(s, 2);
    s += __shfl_xor(s, 4);
    s = s * 0.25f + ews[i] * weh;
    unsigned vv = *(const unsigned*)(Vb + (size_t)dst * 128 + 2 * l);
    float mn = fmaxf(m[0], s);
    float c = __expf(m[0] - mn);
    float p = __expf(s - mn);
    de[0] = de[0] * c + p;
    ax[0] = ax[0] * c + p * bf2f(vv & 0xffffu);
    ay[0] = ay[0] * c + p * bf2f(vv >> 16);
    m[0] = mn;
  }
  // merge the 4 chains
  float M = fmaxf(fmaxf(m[0], m[1]), fmaxf(m[2], m[3]));
  float den = 0.f, AX = 0.f, AY = 0.f;
  if (M > -INFINITY) {
#pragma unroll
    for (int u = 0; u < 4; u++) {
      float c = __expf(m[u] - M);
      den += de[u] * c; AX += ax[u] * c; AY += ay[u] * c;
    }
  }
  float inv = (den > 0.f) ? 1.0f / den : 0.f;
  *(ushort2*)(AGGb + (size_t)n * 128 + 2 * l) = make_ushort2(f2bf(AX * inv), f2bf(AY * inv));
}

// Wo GEMM (bf16 MFMA) + residual + LayerNorm fused. Wave = 16 rows x 128 cols.
__global__ __launch_bounds__(256) void wo_ln_kernel(
    const ushort* __restrict__ AGGb, const ushort* __restrict__ Wob,
    const float* __restrict__ x, const float* __restrict__ gamma,
    const float* __restrict__ beta, float* __restrict__ out, int N) {
  int w = threadIdx.x >> 6, l = threadIdx.x & 63;
  int n0 = blockIdx.x * 64 + w * 16;
  int lr = l & 15, lg = l >> 4;
  short8 a[4];
  const ushort* arow = AGGb + (size_t)(n0 + lr) * 128 + 8 * lg;
#pragma unroll
  for (int ks = 0; ks < 4; ks++) a[ks] = *(const short8*)(arow + 32 * ks);

  f32x4 acc[8];
#pragma unroll
  for (int ct = 0; ct < 8; ct++) {
    acc[ct] = (f32x4){0.f, 0.f, 0.f, 0.f};
    const ushort* wrow = Wob + (size_t)(ct * 16 + lr) * 128 + 8 * lg;
#pragma unroll
    for (int ks = 0; ks < 4; ks++) {
      short8 b = *(const short8*)(wrow + 32 * ks);
      acc[ct] = __builtin_amdgcn_mfma_f32_16x16x32_bf16(a[ks], b, acc[ct], 0, 0, 0);
    }
  }
  float g[8], bt[8];
#pragma unroll
  for (int ct = 0; ct < 8; ct++) { g[ct] = gamma[ct * 16 + lr]; bt[ct] = beta[ct * 16 + lr]; }

#pragma unroll
  for (int r = 0; r < 4; r++) {
    int row = n0 + 4 * lg + r;
    bool ok = row < N;
    float v[8], s = 0.f, s2 = 0.f;
#pragma unroll
    for (int ct = 0; ct < 8; ct++) {
      float xv = ok ? x[(size_t)row * 128 + ct * 16 + lr] : 0.f;
      v[ct] = acc[ct][r] + xv;
      s += v[ct]; s2 += v[ct] * v[ct];
    }
#pragma unroll
    for (int d = 1; d < 16; d <<= 1) { s += __shfl_xor(s, d); s2 += __shfl_xor(s2, d); }
    float mu = s * (1.f / 128.f);
    float var = s2 * (1.f / 128.f) - mu * mu;
    float rs = rsqrtf(var + 1e-5f);
    if (ok) {
#pragma unroll
      for (int ct = 0; ct < 8; ct++)
        out[(size_t)row * 128 + ct * 16 + lr] = (v[ct] - mu) * rs * g[ct] + bt[ct];
    }
  }
}

extern "C" void kernel_launch(void* const* d_in, const int* in_sizes, int n_in,
                              void* d_out, int out_size, void* d_ws, size_t ws_size,
                              hipStream_t stream) {
  const float* x     = (const float*)d_in[0];
  const int*   ei    = (const int*)d_in[1];
  const float* ew    = (const float*)d_in[2];
  const float* Wq    = (const float*)d_in[3];
  const float* Wk    = (const float*)d_in[4];
  const float* Wv    = (const float*)d_in[5];
  const float* We    = (const float*)d_in[6];
  const float* Wo    = (const float*)d_in[7];
  const float* gamma = (const float*)d_in[8];
  const float* beta  = (const float*)d_in[9];

  int N = in_sizes[0] / 128;
  int E = in_sizes[1] / 2;
  int Npad = (N + 63) & ~63;

  char* ws = (char*)d_ws;
  ushort* xb   = (ushort*)ws; ws += (size_t)Npad * 128 * 2;
  ushort* Wb   = (ushort*)ws; ws += 4 * 16384 * 2;          // [Wq,Wk,Wv,Wo] bf16
  float*  Qf   = (float*)ws;  ws += (size_t)Npad * 128 * 4;
  ushort* Kb   = (ushort*)ws; ws += (size_t)Npad * 128 * 2;
  ushort* Vb   = (ushort*)ws; ws += (size_t)Npad * 128 * 2;
  ushort* AGGb = (ushort*)ws; ws += (size_t)Npad * 128 * 2;
  int* cnt  = (int*)ws; ws += (size_t)N * 4;
  int* offs = (int*)ws; ws += (size_t)(N + 1) * 4;
  int* cur  = (int*)ws; ws += (size_t)N * 4;
  int* dsts = (int*)ws; ws += (size_t)E * 4;
  float* ews = (float*)ws; ws += (size_t)E * 4;
  ushort* Wob = Wb + 3 * 16384;

  hipMemsetAsync(cnt, 0, (size_t)N * 4, stream);
  hipMemsetAsync(cur, 0, (size_t)N * 4, stream);

  int ntot = Npad * 128;
  cvt_x_kernel<<<(ntot / 4 + 255) / 256, 256, 0, stream>>>(x, xb, N * 128, ntot);
  cvt_w_kernel<<<(4 * 16384 / 4 + 255) / 256, 256, 0, stream>>>(Wq, Wk, Wv, Wo, Wb);

  qkv_kernel<<<Npad / 64, 256, 0, stream>>>(xb, Wb, Qf, Kb, Vb, N);

  int eblocks = (E + 255) / 256;
  hist_kernel<<<eblocks, 256, 0, stream>>>(ei, cnt, E);
  scan_kernel<<<1, 1024, 0, stream>>>(cnt, offs, N);
  fill_kernel<<<eblocks, 256, 0, stream>>>(ei, ew, offs, cur, dsts, ews, E);

  edge_attn_kernel<<<(N + 3) / 4, 256, 0, stream>>>(Qf, Kb, Vb, dsts, ews, We, offs, AGGb, N);

  wo_ln_kernel<<<Npad / 64, 256, 0, stream>>>(AGGb, Wob, x, gamma, beta, (float*)d_out, N);
}

// Round 3
// 246.170 us; speedup vs baseline: 2.0434x; 1.3159x over previous
//
#include <hip/hip_runtime.h>
#include <hip/hip_bf16.h>
#include <math.h>

// ---------------------------------------------------------------------------
// EdgeAwareAttention: B=1, N=50000, D=128, H=8, d=16, E=800000
//  cvt_x     : x f32 -> bf16 (padded, zero-fill)
//  cvt_w     : Wq,Wk,Wv,Wo f32 -> bf16
//  qkv       : MFMA bf16: Q(f32), K(bf16), V(bf16)
//  hist_rank : cnt histogram by src; rank[e] = old count (the fill position)
//  scan x3   : parallel exclusive scan of cnt -> offs
//  fill      : recs[offs[s]+rank[e]] = {dst, ew}  (one 8B scatter per edge)
//  edge_attn : per-node online softmax, 8 chains, bf16 K/V gathers
//  wo_ln     : MFMA Wo GEMM + residual + LayerNorm fused -> d_out
// ---------------------------------------------------------------------------

typedef __attribute__((ext_vector_type(8))) short short8;
typedef __attribute__((ext_vector_type(4))) float f32x4;

static __device__ __forceinline__ ushort f2bf(float f) {
  unsigned u = __float_as_uint(f);
  u += 0x7fff + ((u >> 16) & 1);          // RNE
  return (ushort)(u >> 16);
}
static __device__ __forceinline__ float bf2f(unsigned hi16) {
  return __uint_as_float(hi16 << 16);
}

__global__ void cvt_x_kernel(const float* __restrict__ x, ushort* __restrict__ xb,
                             int nvalid, int ntot) {
  int i = (blockIdx.x * 256 + threadIdx.x) * 4;
  if (i >= ntot) return;
  ushort4 o;
  if (i < nvalid) {
    float4 v = *(const float4*)(x + i);
    o = make_ushort4(f2bf(v.x), f2bf(v.y), f2bf(v.z), f2bf(v.w));
  } else {
    o = make_ushort4(0, 0, 0, 0);
  }
  *(ushort4*)(xb + i) = o;
}

__global__ void cvt_w_kernel(const float* __restrict__ Wq, const float* __restrict__ Wk,
                             const float* __restrict__ Wv, const float* __restrict__ Wo,
                             ushort* __restrict__ out) {
  int i = (blockIdx.x * 256 + threadIdx.x) * 4;
  if (i >= 4 * 16384) return;
  const float* src = (i < 16384) ? Wq : (i < 32768) ? Wk : (i < 49152) ? Wv : Wo;
  int off = i & 16383;
  float4 v = *(const float4*)(src + off);
  *(ushort4*)(out + i) = make_ushort4(f2bf(v.x), f2bf(v.y), f2bf(v.z), f2bf(v.w));
}

// Q/K/V fused MFMA GEMM. Block = 256 thr = 4 waves; wave computes 16 rows x 384 cols.
__global__ __launch_bounds__(256) void qkv_kernel(
    const ushort* __restrict__ xb, const ushort* __restrict__ Wb,   // Wb: [3][128][128]
    float* __restrict__ Qf, ushort* __restrict__ Kb, ushort* __restrict__ Vb, int N) {
  int w = threadIdx.x >> 6, l = threadIdx.x & 63;
  int n0 = blockIdx.x * 64 + w * 16;
  int lr = l & 15, lg = l >> 4;
  short8 a[4];
  const ushort* xrow = xb + (size_t)(n0 + lr) * 128 + 8 * lg;
#pragma unroll
  for (int ks = 0; ks < 4; ks++) a[ks] = *(const short8*)(xrow + 32 * ks);

#pragma unroll
  for (int m = 0; m < 3; m++) {
    const ushort* Wm = Wb + m * 16384;
#pragma unroll
    for (int ct = 0; ct < 8; ct++) {
      f32x4 acc = {0.f, 0.f, 0.f, 0.f};
      const ushort* wrow = Wm + (size_t)(ct * 16 + lr) * 128 + 8 * lg;
#pragma unroll
      for (int ks = 0; ks < 4; ks++) {
        short8 b = *(const short8*)(wrow + 32 * ks);
        acc = __builtin_amdgcn_mfma_f32_16x16x32_bf16(a[ks], b, acc, 0, 0, 0);
      }
      int c = ct * 16 + lr;
#pragma unroll
      for (int r = 0; r < 4; r++) {
        int row = n0 + 4 * lg + r;
        if (row < N) {
          if (m == 0)      Qf[(size_t)row * 128 + c] = acc[r];
          else if (m == 1) Kb[(size_t)row * 128 + c] = f2bf(acc[r]);
          else             Vb[(size_t)row * 128 + c] = f2bf(acc[r]);
        }
      }
    }
  }
}

__global__ void hist_rank_kernel(const int* __restrict__ ei, int* __restrict__ cnt,
                                 int* __restrict__ rank, int E) {
  int e = blockIdx.x * blockDim.x + threadIdx.x;
  if (e < E) rank[e] = atomicAdd(&cnt[ei[e]], 1);
}

// ---- parallel scan: cnt[0..N) -> offs (exclusive), offs[N] = total ----
static __device__ __forceinline__ int wave_incl_scan(int v, int lane) {
#pragma unroll
  for (int d = 1; d < 64; d <<= 1) {
    int u = __shfl_up(v, d);
    if (lane >= d) v += u;
  }
  return v;
}

// block-wide (256 thr) scan; returns exclusive prefix, *tot = block total
static __device__ __forceinline__ int block_excl_scan(int v, int* tot) {
  __shared__ int wsum[5];
  int lane = threadIdx.x & 63, wid = threadIdx.x >> 6;
  int incl = wave_incl_scan(v, lane);
  if (lane == 63) wsum[wid] = incl;
  __syncthreads();
  if (threadIdx.x == 0) {
    int a = 0;
#pragma unroll
    for (int w = 0; w < 4; w++) { int t = wsum[w]; wsum[w] = a; a += t; }
    wsum[4] = a;
  }
  __syncthreads();
  *tot = wsum[4];
  return incl - v + wsum[wid];
}

__global__ __launch_bounds__(256) void scan_sums_kernel(
    const int* __restrict__ cnt, int* __restrict__ bsum, int N) {
  int i = blockIdx.x * 256 + threadIdx.x;
  int v = (i < N) ? cnt[i] : 0;
  int tot;
  block_excl_scan(v, &tot);
  if (threadIdx.x == 0) bsum[blockIdx.x] = tot;
}

__global__ __launch_bounds__(256) void scan_tops_kernel(
    const int* __restrict__ bsum, int* __restrict__ bpre, int* __restrict__ offs,
    int NB, int N) {
  int t = threadIdx.x;
  int v = (t < NB) ? bsum[t] : 0;
  int tot;
  int ex = block_excl_scan(v, &tot);
  if (t < NB) bpre[t] = ex;
  if (t == 0) offs[N] = tot;
}

__global__ __launch_bounds__(256) void scan_final_kernel(
    const int* __restrict__ cnt, const int* __restrict__ bpre,
    int* __restrict__ offs, int N) {
  int i = blockIdx.x * 256 + threadIdx.x;
  int v = (i < N) ? cnt[i] : 0;
  int tot;
  int ex = block_excl_scan(v, &tot);
  if (i < N) offs[i] = bpre[blockIdx.x] + ex;
}

__global__ void fill_kernel(const int* __restrict__ ei, const float* __restrict__ ew,
                            const int* __restrict__ offs, const int* __restrict__ rank,
                            int2* __restrict__ recs, int E) {
  int e = blockIdx.x * blockDim.x + threadIdx.x;
  if (e < E) {
    int s = ei[e];
    int pos = offs[s] + rank[e];
    recs[pos] = make_int2(ei[E + e], __float_as_int(ew[e]));
  }
}

// 4 nodes per block (1 wave each). Lane l owns dims {2l,2l+1}; head = l>>3.
// 8 independent online-softmax chains; padded unroll with clamped index.
__global__ __launch_bounds__(256) void edge_attn_kernel(
    const float* __restrict__ Q, const ushort* __restrict__ Kb, const ushort* __restrict__ Vb,
    const int2* __restrict__ recs, const float* __restrict__ We,
    const int* __restrict__ offs, ushort* __restrict__ AGGb, int N) {
  int wv = threadIdx.x >> 6, l = threadIdx.x & 63;
  int n = blockIdx.x * 4 + wv;
  if (n >= N) return;
  int h = l >> 3;
  float2 q = *(const float2*)(Q + (size_t)n * 128 + 2 * l);
  float weh = We[h];
  int o0 = offs[n], o1 = offs[n + 1];

  float m[8], de[8], ax[8], ay[8];
#pragma unroll
  for (int u = 0; u < 8; u++) { m[u] = -INFINITY; de[u] = 0.f; ax[u] = 0.f; ay[u] = 0.f; }

  for (int i = o0; i < o1; i += 8) {
    int2 rec[8];
#pragma unroll
    for (int u = 0; u < 8; u++) {
      int idx = (i + u < o1) ? i + u : o1 - 1;
      rec[u] = recs[idx];
    }
    unsigned kk[8], vv[8];
#pragma unroll
    for (int u = 0; u < 8; u++) kk[u] = *(const unsigned*)(Kb + (size_t)rec[u].x * 128 + 2 * l);
#pragma unroll
    for (int u = 0; u < 8; u++) vv[u] = *(const unsigned*)(Vb + (size_t)rec[u].x * 128 + 2 * l);
#pragma unroll
    for (int u = 0; u < 8; u++) {
      float kx = bf2f(kk[u] & 0xffffu), ky = bf2f(kk[u] >> 16);
      float s = q.x * kx + q.y * ky;
      s += __shfl_xor(s, 1);
      s += __shfl_xor(s, 2);
      s += __shfl_xor(s, 4);
      s = s * 0.25f + __int_as_float(rec[u].y) * weh;
      if (i + u >= o1) s = -INFINITY;
      float vx = bf2f(vv[u] & 0xffffu), vy = bf2f(vv[u] >> 16);
      float mn = fmaxf(m[u], s);
      float c = __expf(m[u] - mn);
      float p = __expf(s - mn);
      de[u] = de[u] * c + p;
      ax[u] = ax[u] * c + p * vx;
      ay[u] = ay[u] * c + p * vy;
      m[u] = mn;
    }
  }
  // merge the 8 chains
  float M = m[0];
#pragma unroll
  for (int u = 1; u < 8; u++) M = fmaxf(M, m[u]);
  float den = 0.f, AX = 0.f, AY = 0.f;
  if (M > -INFINITY) {
#pragma unroll
    for (int u = 0; u < 8; u++) {
      if (m[u] > -INFINITY) {
        float c = __expf(m[u] - M);
        den += de[u] * c; AX += ax[u] * c; AY += ay[u] * c;
      }
    }
  }
  float inv = (den > 0.f) ? 1.0f / den : 0.f;
  *(ushort2*)(AGGb + (size_t)n * 128 + 2 * l) = make_ushort2(f2bf(AX * inv), f2bf(AY * inv));
}

// Wo GEMM (bf16 MFMA) + residual + LayerNorm fused. Wave = 16 rows x 128 cols.
__global__ __launch_bounds__(256) void wo_ln_kernel(
    const ushort* __restrict__ AGGb, const ushort* __restrict__ Wob,
    const float* __restrict__ x, const float* __restrict__ gamma,
    const float* __restrict__ beta, float* __restrict__ out, int N) {
  int w = threadIdx.x >> 6, l = threadIdx.x & 63;
  int n0 = blockIdx.x * 64 + w * 16;
  int lr = l & 15, lg = l >> 4;
  short8 a[4];
  const ushort* arow = AGGb + (size_t)(n0 + lr) * 128 + 8 * lg;
#pragma unroll
  for (int ks = 0; ks < 4; ks++) a[ks] = *(const short8*)(arow + 32 * ks);

  f32x4 acc[8];
#pragma unroll
  for (int ct = 0; ct < 8; ct++) {
    acc[ct] = (f32x4){0.f, 0.f, 0.f, 0.f};
    const ushort* wrow = Wob + (size_t)(ct * 16 + lr) * 128 + 8 * lg;
#pragma unroll
    for (int ks = 0; ks < 4; ks++) {
      short8 b = *(const short8*)(wrow + 32 * ks);
      acc[ct] = __builtin_amdgcn_mfma_f32_16x16x32_bf16(a[ks], b, acc[ct], 0, 0, 0);
    }
  }
  float g[8], bt[8];
#pragma unroll
  for (int ct = 0; ct < 8; ct++) { g[ct] = gamma[ct * 16 + lr]; bt[ct] = beta[ct * 16 + lr]; }

#pragma unroll
  for (int r = 0; r < 4; r++) {
    int row = n0 + 4 * lg + r;
    bool ok = row < N;
    float v[8], s = 0.f, s2 = 0.f;
#pragma unroll
    for (int ct = 0; ct < 8; ct++) {
      float xv = ok ? x[(size_t)row * 128 + ct * 16 + lr] : 0.f;
      v[ct] = acc[ct][r] + xv;
      s += v[ct]; s2 += v[ct] * v[ct];
    }
#pragma unroll
    for (int d = 1; d < 16; d <<= 1) { s += __shfl_xor(s, d); s2 += __shfl_xor(s2, d); }
    float mu = s * (1.f / 128.f);
    float var = s2 * (1.f / 128.f) - mu * mu;
    float rs = rsqrtf(var + 1e-5f);
    if (ok) {
#pragma unroll
      for (int ct = 0; ct < 8; ct++)
        out[(size_t)row * 128 + ct * 16 + lr] = (v[ct] - mu) * rs * g[ct] + bt[ct];
    }
  }
}

extern "C" void kernel_launch(void* const* d_in, const int* in_sizes, int n_in,
                              void* d_out, int out_size, void* d_ws, size_t ws_size,
                              hipStream_t stream) {
  const float* x     = (const float*)d_in[0];
  const int*   ei    = (const int*)d_in[1];
  const float* ew    = (const float*)d_in[2];
  const float* Wq    = (const float*)d_in[3];
  const float* Wk    = (const float*)d_in[4];
  const float* Wv    = (const float*)d_in[5];
  const float* We    = (const float*)d_in[6];
  const float* Wo    = (const float*)d_in[7];
  const float* gamma = (const float*)d_in[8];
  const float* beta  = (const float*)d_in[9];

  int N = in_sizes[0] / 128;
  int E = in_sizes[1] / 2;
  int Npad = (N + 63) & ~63;
  int NB = (N + 255) / 256;

  char* ws = (char*)d_ws;
  ushort* xb   = (ushort*)ws; ws += (size_t)Npad * 128 * 2;
  ushort* Wb   = (ushort*)ws; ws += 4 * 16384 * 2;          // [Wq,Wk,Wv,Wo] bf16
  float*  Qf   = (float*)ws;  ws += (size_t)Npad * 128 * 4;
  ushort* Kb   = (ushort*)ws; ws += (size_t)Npad * 128 * 2;
  ushort* Vb   = (ushort*)ws; ws += (size_t)Npad * 128 * 2;
  ushort* AGGb = (ushort*)ws; ws += (size_t)Npad * 128 * 2;
  int* cnt  = (int*)ws; ws += (size_t)N * 4;
  int* offs = (int*)ws; ws += (size_t)(N + 1) * 4;
  int* rank = (int*)ws; ws += (size_t)E * 4;
  int2* recs = (int2*)ws; ws += (size_t)E * 8;
  int* bsum = (int*)ws; ws += 256 * 4;
  int* bpre = (int*)ws; ws += 256 * 4;
  ushort* Wob = Wb + 3 * 16384;

  hipMemsetAsync(cnt, 0, (size_t)N * 4, stream);

  int ntot = Npad * 128;
  cvt_x_kernel<<<(ntot / 4 + 255) / 256, 256, 0, stream>>>(x, xb, N * 128, ntot);
  cvt_w_kernel<<<(4 * 16384 / 4 + 255) / 256, 256, 0, stream>>>(Wq, Wk, Wv, Wo, Wb);

  qkv_kernel<<<Npad / 64, 256, 0, stream>>>(xb, Wb, Qf, Kb, Vb, N);

  int eblocks = (E + 255) / 256;
  hist_rank_kernel<<<eblocks, 256, 0, stream>>>(ei, cnt, rank, E);
  scan_sums_kernel<<<NB, 256, 0, stream>>>(cnt, bsum, N);
  scan_tops_kernel<<<1, 256, 0, stream>>>(bsum, bpre, offs, NB, N);
  scan_final_kernel<<<NB, 256, 0, stream>>>(cnt, bpre, offs, N);
  fill_kernel<<<eblocks, 256, 0, stream>>>(ei, ew, offs, rank, recs, E);

  edge_attn_kernel<<<(N + 3) / 4, 256, 0, stream>>>(Qf, Kb, Vb, recs, We, offs, AGGb, N);

  wo_ln_kernel<<<Npad / 64, 256, 0, stream>>>(AGGb, Wob, x, gamma, beta, (float*)d_out, N);
}

// Round 4
// 210.039 us; speedup vs baseline: 2.3949x; 1.1720x over previous
//
#include <hip/hip_runtime.h>
#include <hip/hip_bf16.h>
#include <math.h>

// ---------------------------------------------------------------------------
// EdgeAwareAttention: B=1, N=50000, D=128, H=8, d=16, E=800000
//  prep      : Wq,Wk,Wv,Wo f32->bf16 + zero cnt
//  qkv_hist  : [blocks 0..QB) MFMA QKV from f32 x (inline cvt) -> Qf f32, KV bf16
//              [blocks QB..)  edge histogram by src + rank[e]
//  scan x3   : parallel exclusive scan of cnt -> offs
//  fill      : recs[offs[s]+rank[e]] = {dst, ew}
//  edge_attn : lane-per-(node,head): 8 lanes/node, no shuffles, defer-max
//  wo_ln     : MFMA Wo GEMM + residual + LayerNorm fused -> d_out
// ---------------------------------------------------------------------------

typedef __attribute__((ext_vector_type(8))) short short8;
typedef __attribute__((ext_vector_type(4))) float f32x4;

static __device__ __forceinline__ ushort f2bf(float f) {
  unsigned u = __float_as_uint(f);
  u += 0x7fff + ((u >> 16) & 1);          // RNE
  return (ushort)(u >> 16);
}
static __device__ __forceinline__ float bflo(unsigned u) {   // low bf16 -> f32
  return __uint_as_float(u << 16);
}
static __device__ __forceinline__ float bfhi(unsigned u) {   // high bf16 -> f32
  return __uint_as_float(u & 0xffff0000u);
}

// W convert (4*16384 elems, 64 blocks' worth) + cnt zero
__global__ __launch_bounds__(256) void prep_kernel(
    const float* __restrict__ Wq, const float* __restrict__ Wk,
    const float* __restrict__ Wv, const float* __restrict__ Wo,
    ushort* __restrict__ Wb, int* __restrict__ cnt, int N) {
  int tid = blockIdx.x * 256 + threadIdx.x;
  if (tid < 16384) {
    int i = tid * 4;
    const float* src = (i < 16384) ? Wq : (i < 32768) ? Wk : (i < 49152) ? Wv : Wo;
    int off = i & 16383;
    float4 v = *(const float4*)(src + off);
    *(ushort4*)(Wb + i) = make_ushort4(f2bf(v.x), f2bf(v.y), f2bf(v.z), f2bf(v.w));
  } else {
    int j = tid - 16384;                   // zero cnt, 4 ints each
    int4 z = make_int4(0, 0, 0, 0);
    if (j * 4 + 3 < N) *(int4*)(cnt + j * 4) = z;
    else for (int k = j * 4; k < N; k++) if (k >= j * 4 && k < j * 4 + 4) cnt[k] = 0;
  }
}

// Fused: QKV MFMA GEMM (blocks < QB) | edge histogram+rank (blocks >= QB).
// qkv: block = 4 waves; wave computes 16 rows x 384 cols. Inline f32->bf16 A.
// KVb layout: row n = [K[0..128) | V[0..128)] (256 ushorts).
__global__ __launch_bounds__(256) void qkv_hist_kernel(
    const float* __restrict__ x, const ushort* __restrict__ Wb,   // Wb: [3][128][128]
    float* __restrict__ Qf, ushort* __restrict__ KVb,
    const int* __restrict__ ei, int* __restrict__ cnt, int* __restrict__ rank,
    int N, int E, int QB) {
  if ((int)blockIdx.x >= QB) {
    int e = ((int)blockIdx.x - QB) * 256 + threadIdx.x;
    if (e < E) rank[e] = atomicAdd(&cnt[ei[e]], 1);
    return;
  }
  int w = threadIdx.x >> 6, l = threadIdx.x & 63;
  int n0 = blockIdx.x * 64 + w * 16;
  int lr = l & 15, lg = l >> 4;
  int arow = n0 + lr;
  short8 a[4];
  if (arow < N) {
    const float* xrow = x + (size_t)arow * 128 + 8 * lg;
#pragma unroll
    for (int ks = 0; ks < 4; ks++) {
      float4 x0 = *(const float4*)(xrow + 32 * ks);
      float4 x1 = *(const float4*)(xrow + 32 * ks + 4);
      short8 t;
      t[0] = f2bf(x0.x); t[1] = f2bf(x0.y); t[2] = f2bf(x0.z); t[3] = f2bf(x0.w);
      t[4] = f2bf(x1.x); t[5] = f2bf(x1.y); t[6] = f2bf(x1.z); t[7] = f2bf(x1.w);
      a[ks] = t;
    }
  } else {
#pragma unroll
    for (int ks = 0; ks < 4; ks++) a[ks] = (short8){0,0,0,0,0,0,0,0};
  }

#pragma unroll
  for (int m = 0; m < 3; m++) {
    const ushort* Wm = Wb + m * 16384;
#pragma unroll
    for (int ct = 0; ct < 8; ct++) {
      f32x4 acc = {0.f, 0.f, 0.f, 0.f};
      const ushort* wrow = Wm + (size_t)(ct * 16 + lr) * 128 + 8 * lg;
#pragma unroll
      for (int ks = 0; ks < 4; ks++) {
        short8 b = *(const short8*)(wrow + 32 * ks);
        acc = __builtin_amdgcn_mfma_f32_16x16x32_bf16(a[ks], b, acc, 0, 0, 0);
      }
      int c = ct * 16 + lr;
#pragma unroll
      for (int r = 0; r < 4; r++) {
        int row = n0 + 4 * lg + r;
        if (row < N) {
          if (m == 0)      Qf[(size_t)row * 128 + c] = acc[r];
          else if (m == 1) KVb[(size_t)row * 256 + c] = f2bf(acc[r]);
          else             KVb[(size_t)row * 256 + 128 + c] = f2bf(acc[r]);
        }
      }
    }
  }
}

// ---- parallel scan: cnt[0..N) -> offs (exclusive), offs[N] = total ----
static __device__ __forceinline__ int wave_incl_scan(int v, int lane) {
#pragma unroll
  for (int d = 1; d < 64; d <<= 1) {
    int u = __shfl_up(v, d);
    if (lane >= d) v += u;
  }
  return v;
}

static __device__ __forceinline__ int block_excl_scan(int v, int* tot) {
  __shared__ int wsum[5];
  int lane = threadIdx.x & 63, wid = threadIdx.x >> 6;
  int incl = wave_incl_scan(v, lane);
  if (lane == 63) wsum[wid] = incl;
  __syncthreads();
  if (threadIdx.x == 0) {
    int a = 0;
#pragma unroll
    for (int w = 0; w < 4; w++) { int t = wsum[w]; wsum[w] = a; a += t; }
    wsum[4] = a;
  }
  __syncthreads();
  *tot = wsum[4];
  return incl - v + wsum[wid];
}

__global__ __launch_bounds__(256) void scan_sums_kernel(
    const int* __restrict__ cnt, int* __restrict__ bsum, int N) {
  int i = blockIdx.x * 256 + threadIdx.x;
  int v = (i < N) ? cnt[i] : 0;
  int tot;
  block_excl_scan(v, &tot);
  if (threadIdx.x == 0) bsum[blockIdx.x] = tot;
}

__global__ __launch_bounds__(256) void scan_tops_kernel(
    const int* __restrict__ bsum, int* __restrict__ bpre, int* __restrict__ offs,
    int NB, int N) {
  int t = threadIdx.x;
  int v = (t < NB) ? bsum[t] : 0;
  int tot;
  int ex = block_excl_scan(v, &tot);
  if (t < NB) bpre[t] = ex;
  if (t == 0) offs[N] = tot;
}

__global__ __launch_bounds__(256) void scan_final_kernel(
    const int* __restrict__ cnt, const int* __restrict__ bpre,
    int* __restrict__ offs, int N) {
  int i = blockIdx.x * 256 + threadIdx.x;
  int v = (i < N) ? cnt[i] : 0;
  int tot;
  int ex = block_excl_scan(v, &tot);
  if (i < N) offs[i] = bpre[blockIdx.x] + ex;
}

__global__ void fill_kernel(const int* __restrict__ ei, const float* __restrict__ ew,
                            const int* __restrict__ offs, const int* __restrict__ rank,
                            int2* __restrict__ recs, int E) {
  int e = blockIdx.x * blockDim.x + threadIdx.x;
  if (e < E) {
    int s = ei[e];
    int pos = offs[s] + rank[e];
    recs[pos] = make_int2(ei[E + e], __float_as_int(ew[e]));
  }
}

// Lane-per-(node,head): 8 lanes per node, lane owns one head's 16 dims.
// Block 256 thr = 32 nodes. No cross-lane ops; defer-max rescale (THR=8, exact).
__global__ __launch_bounds__(256) void edge_attn_kernel(
    const float* __restrict__ Qf, const ushort* __restrict__ KVb,
    const int2* __restrict__ recs, const float* __restrict__ We,
    const int* __restrict__ offs, ushort* __restrict__ AGGb, int N) {
  int t = threadIdx.x;
  int g = t >> 3;                 // node sub-index (0..31)
  int h = t & 7;                  // head
  int n = blockIdx.x * 32 + g;
  if (n >= N) return;

  float q[16];
  const float* qp = Qf + (size_t)n * 128 + h * 16;
  *(float4*)(q + 0)  = *(const float4*)(qp + 0);
  *(float4*)(q + 4)  = *(const float4*)(qp + 4);
  *(float4*)(q + 8)  = *(const float4*)(qp + 8);
  *(float4*)(q + 12) = *(const float4*)(qp + 12);
  float weh = We[h];
  int o0 = offs[n], o1 = offs[n + 1];

  float m = -INFINITY, de = 0.f;
  float acc[16];
#pragma unroll
  for (int d = 0; d < 16; d++) acc[d] = 0.f;

  unsigned hoff = (unsigned)(h << 4);
#pragma unroll 2
  for (int i = o0; i < o1; i++) {
    int2 rec = recs[i];
    const ushort* kv = KVb + (((unsigned)rec.x << 8) + hoff);
    uint4 k0 = *(const uint4*)kv;            // dims 0..7 (bf16 pairs)
    uint4 k1 = *(const uint4*)(kv + 8);      // dims 8..15
    float s;
    s  = q[0]  * bflo(k0.x) + q[1]  * bfhi(k0.x);
    s += q[2]  * bflo(k0.y) + q[3]  * bfhi(k0.y);
    s += q[4]  * bflo(k0.z) + q[5]  * bfhi(k0.z);
    s += q[6]  * bflo(k0.w) + q[7]  * bfhi(k0.w);
    s += q[8]  * bflo(k1.x) + q[9]  * bfhi(k1.x);
    s += q[10] * bflo(k1.y) + q[11] * bfhi(k1.y);
    s += q[12] * bflo(k1.z) + q[13] * bfhi(k1.z);
    s += q[14] * bflo(k1.w) + q[15] * bfhi(k1.w);
    s = s * 0.25f + __int_as_float(rec.y) * weh;

    float p;
    if (s > m + 8.f) {                       // rescale path (rare after warmup)
      float c = __expf(m - s);               // exp(-inf)=0 on first edge
      de *= c;
#pragma unroll
      for (int d = 0; d < 16; d++) acc[d] *= c;
      m = s;
      p = 1.f;
    } else {
      p = __expf(s - m);                     // bounded by e^8
    }
    de += p;

    uint4 v0 = *(const uint4*)(kv + 128);
    uint4 v1 = *(const uint4*)(kv + 136);
    acc[0]  += p * bflo(v0.x); acc[1]  += p * bfhi(v0.x);
    acc[2]  += p * bflo(v0.y); acc[3]  += p * bfhi(v0.y);
    acc[4]  += p * bflo(v0.z); acc[5]  += p * bfhi(v0.z);
    acc[6]  += p * bflo(v0.w); acc[7]  += p * bfhi(v0.w);
    acc[8]  += p * bflo(v1.x); acc[9]  += p * bfhi(v1.x);
    acc[10] += p * bflo(v1.y); acc[11] += p * bfhi(v1.y);
    acc[12] += p * bflo(v1.z); acc[13] += p * bfhi(v1.z);
    acc[14] += p * bflo(v1.w); acc[15] += p * bfhi(v1.w);
  }

  float inv = (de > 0.f) ? 1.0f / de : 0.f;
  unsigned o[8];
#pragma unroll
  for (int j = 0; j < 8; j++) {
    ushort lo = f2bf(acc[2 * j] * inv);
    ushort hi = f2bf(acc[2 * j + 1] * inv);
    o[j] = (unsigned)lo | ((unsigned)hi << 16);
  }
  ushort* op = AGGb + (size_t)n * 128 + h * 16;
  *(uint4*)(op + 0) = make_uint4(o[0], o[1], o[2], o[3]);
  *(uint4*)(op + 8) = make_uint4(o[4], o[5], o[6], o[7]);
}

// Wo GEMM (bf16 MFMA) + residual + LayerNorm fused. Wave = 16 rows x 128 cols.
__global__ __launch_bounds__(256) void wo_ln_kernel(
    const ushort* __restrict__ AGGb, const ushort* __restrict__ Wob,
    const float* __restrict__ x, const float* __restrict__ gamma,
    const float* __restrict__ beta, float* __restrict__ out, int N) {
  int w = threadIdx.x >> 6, l = threadIdx.x & 63;
  int n0 = blockIdx.x * 64 + w * 16;
  int lr = l & 15, lg = l >> 4;
  short8 a[4];
  const ushort* arow = AGGb + (size_t)(n0 + lr) * 128 + 8 * lg;
#pragma unroll
  for (int ks = 0; ks < 4; ks++) a[ks] = *(const short8*)(arow + 32 * ks);

  f32x4 acc[8];
#pragma unroll
  for (int ct = 0; ct < 8; ct++) {
    acc[ct] = (f32x4){0.f, 0.f, 0.f, 0.f};
    const ushort* wrow = Wob + (size_t)(ct * 16 + lr) * 128 + 8 * lg;
#pragma unroll
    for (int ks = 0; ks < 4; ks++) {
      short8 b = *(const short8*)(wrow + 32 * ks);
      acc[ct] = __builtin_amdgcn_mfma_f32_16x16x32_bf16(a[ks], b, acc[ct], 0, 0, 0);
    }
  }
  float g[8], bt[8];
#pragma unroll
  for (int ct = 0; ct < 8; ct++) { g[ct] = gamma[ct * 16 + lr]; bt[ct] = beta[ct * 16 + lr]; }

#pragma unroll
  for (int r = 0; r < 4; r++) {
    int row = n0 + 4 * lg + r;
    bool ok = row < N;
    float v[8], s = 0.f, s2 = 0.f;
#pragma unroll
    for (int ct = 0; ct < 8; ct++) {
      float xv = ok ? x[(size_t)row * 128 + ct * 16 + lr] : 0.f;
      v[ct] = acc[ct][r] + xv;
      s += v[ct]; s2 += v[ct] * v[ct];
    }
#pragma unroll
    for (int d = 1; d < 16; d <<= 1) { s += __shfl_xor(s, d); s2 += __shfl_xor(s2, d); }
    float mu = s * (1.f / 128.f);
    float var = s2 * (1.f / 128.f) - mu * mu;
    float rs = rsqrtf(var + 1e-5f);
    if (ok) {
#pragma unroll
      for (int ct = 0; ct < 8; ct++)
        out[(size_t)row * 128 + ct * 16 + lr] = (v[ct] - mu) * rs * g[ct] + bt[ct];
    }
  }
}

extern "C" void kernel_launch(void* const* d_in, const int* in_sizes, int n_in,
                              void* d_out, int out_size, void* d_ws, size_t ws_size,
                              hipStream_t stream) {
  const float* x     = (const float*)d_in[0];
  const int*   ei    = (const int*)d_in[1];
  const float* ew    = (const float*)d_in[2];
  const float* Wq    = (const float*)d_in[3];
  const float* Wk    = (const float*)d_in[4];
  const float* Wv    = (const float*)d_in[5];
  const float* We    = (const float*)d_in[6];
  const float* Wo    = (const float*)d_in[7];
  const float* gamma = (const float*)d_in[8];
  const float* beta  = (const float*)d_in[9];

  int N = in_sizes[0] / 128;
  int E = in_sizes[1] / 2;
  int Npad = (N + 63) & ~63;
  int NB = (N + 255) / 256;
  int QB = Npad / 64;
  int EB = (E + 255) / 256;

  char* ws = (char*)d_ws;
  ushort* Wb   = (ushort*)ws; ws += 4 * 16384 * 2;          // [Wq,Wk,Wv,Wo] bf16
  float*  Qf   = (float*)ws;  ws += (size_t)Npad * 128 * 4;
  ushort* KVb  = (ushort*)ws; ws += (size_t)Npad * 256 * 2; // [K row | V row]
  ushort* AGGb = (ushort*)ws; ws += (size_t)Npad * 128 * 2;
  int* cnt  = (int*)ws; ws += (size_t)N * 4;
  int* offs = (int*)ws; ws += (size_t)(N + 1) * 4;
  int* rank = (int*)ws; ws += (size_t)E * 4;
  int2* recs = (int2*)ws; ws += (size_t)E * 8;
  int* bsum = (int*)ws; ws += 256 * 4;
  int* bpre = (int*)ws; ws += 256 * 4;
  ushort* Wob = Wb + 3 * 16384;

  int prep_threads = 16384 + (N + 3) / 4;
  prep_kernel<<<(prep_threads + 255) / 256, 256, 0, stream>>>(Wq, Wk, Wv, Wo, Wb, cnt, N);

  qkv_hist_kernel<<<QB + EB, 256, 0, stream>>>(x, Wb, Qf, KVb, ei, cnt, rank, N, E, QB);

  scan_sums_kernel<<<NB, 256, 0, stream>>>(cnt, bsum, N);
  scan_tops_kernel<<<1, 256, 0, stream>>>(bsum, bpre, offs, NB, N);
  scan_final_kernel<<<NB, 256, 0, stream>>>(cnt, bpre, offs, N);
  fill_kernel<<<EB, 256, 0, stream>>>(ei, ew, offs, rank, recs, E);

  edge_attn_kernel<<<(N + 31) / 32, 256, 0, stream>>>(Qf, KVb, recs, We, offs, AGGb, N);

  wo_ln_kernel<<<Npad / 64, 256, 0, stream>>>(AGGb, Wob, x, gamma, beta, (float*)d_out, N);
}

// Round 5
// 190.425 us; speedup vs baseline: 2.6416x; 1.1030x over previous
//
#include <hip/hip_runtime.h>
#include <hip/hip_bf16.h>
#include <math.h>

// ---------------------------------------------------------------------------
// EdgeAwareAttention: B=1, N=50000, D=128, H=8, d=16, E=800000
//  prep      : Wq,Wk,Wv,Wo f32->bf16 + zero cnt
//  qkv_hist  : [blocks 0..QB) MFMA QKV from f32 x (inline cvt) -> Qf f32, KV bf16
//              [blocks QB..)  edge histogram by src + rank[e]
//  scan x3   : parallel exclusive scan of cnt -> offs
//  fill      : recs[offs[s]+rank[e]] = {dst, ew}
//  edge_attn : lane-per-(node,head), batch-4 edge loads for MLP, defer-max
//  wo_ln     : MFMA Wo GEMM + residual + LayerNorm fused -> d_out
// ---------------------------------------------------------------------------

typedef __attribute__((ext_vector_type(8))) short short8;
typedef __attribute__((ext_vector_type(4))) float f32x4;

static __device__ __forceinline__ ushort f2bf(float f) {
  unsigned u = __float_as_uint(f);
  u += 0x7fff + ((u >> 16) & 1);          // RNE
  return (ushort)(u >> 16);
}
static __device__ __forceinline__ float bflo(unsigned u) {   // low bf16 -> f32
  return __uint_as_float(u << 16);
}
static __device__ __forceinline__ float bfhi(unsigned u) {   // high bf16 -> f32
  return __uint_as_float(u & 0xffff0000u);
}

// W convert (4*16384 elems) + cnt zero
__global__ __launch_bounds__(256) void prep_kernel(
    const float* __restrict__ Wq, const float* __restrict__ Wk,
    const float* __restrict__ Wv, const float* __restrict__ Wo,
    ushort* __restrict__ Wb, int* __restrict__ cnt, int N) {
  int tid = blockIdx.x * 256 + threadIdx.x;
  if (tid < 16384) {
    int i = tid * 4;
    const float* src = (i < 16384) ? Wq : (i < 32768) ? Wk : (i < 49152) ? Wv : Wo;
    int off = i & 16383;
    float4 v = *(const float4*)(src + off);
    *(ushort4*)(Wb + i) = make_ushort4(f2bf(v.x), f2bf(v.y), f2bf(v.z), f2bf(v.w));
  } else {
    int j = tid - 16384;
    int base = j * 4;
    if (base + 3 < N) *(int4*)(cnt + base) = make_int4(0, 0, 0, 0);
    else if (base < N) { for (int k = base; k < N; k++) cnt[k] = 0; }
  }
}

// Fused: QKV MFMA GEMM (blocks < QB) | edge histogram+rank (blocks >= QB).
// KVb layout: row n = [K[0..128) | V[0..128)] (256 ushorts).
__global__ __launch_bounds__(256) void qkv_hist_kernel(
    const float* __restrict__ x, const ushort* __restrict__ Wb,   // Wb: [3][128][128]
    float* __restrict__ Qf, ushort* __restrict__ KVb,
    const int* __restrict__ ei, int* __restrict__ cnt, int* __restrict__ rank,
    int N, int E, int QB) {
  if ((int)blockIdx.x >= QB) {
    int e = ((int)blockIdx.x - QB) * 256 + threadIdx.x;
    if (e < E) rank[e] = atomicAdd(&cnt[ei[e]], 1);
    return;
  }
  int w = threadIdx.x >> 6, l = threadIdx.x & 63;
  int n0 = blockIdx.x * 64 + w * 16;
  int lr = l & 15, lg = l >> 4;
  int arow = n0 + lr;
  short8 a[4];
  if (arow < N) {
    const float* xrow = x + (size_t)arow * 128 + 8 * lg;
#pragma unroll
    for (int ks = 0; ks < 4; ks++) {
      float4 x0 = *(const float4*)(xrow + 32 * ks);
      float4 x1 = *(const float4*)(xrow + 32 * ks + 4);
      short8 t;
      t[0] = f2bf(x0.x); t[1] = f2bf(x0.y); t[2] = f2bf(x0.z); t[3] = f2bf(x0.w);
      t[4] = f2bf(x1.x); t[5] = f2bf(x1.y); t[6] = f2bf(x1.z); t[7] = f2bf(x1.w);
      a[ks] = t;
    }
  } else {
#pragma unroll
    for (int ks = 0; ks < 4; ks++) a[ks] = (short8){0,0,0,0,0,0,0,0};
  }

#pragma unroll
  for (int m = 0; m < 3; m++) {
    const ushort* Wm = Wb + m * 16384;
#pragma unroll
    for (int ct = 0; ct < 8; ct++) {
      f32x4 acc = {0.f, 0.f, 0.f, 0.f};
      const ushort* wrow = Wm + (size_t)(ct * 16 + lr) * 128 + 8 * lg;
#pragma unroll
      for (int ks = 0; ks < 4; ks++) {
        short8 b = *(const short8*)(wrow + 32 * ks);
        acc = __builtin_amdgcn_mfma_f32_16x16x32_bf16(a[ks], b, acc, 0, 0, 0);
      }
      int c = ct * 16 + lr;
#pragma unroll
      for (int r = 0; r < 4; r++) {
        int row = n0 + 4 * lg + r;
        if (row < N) {
          if (m == 0)      Qf[(size_t)row * 128 + c] = acc[r];
          else if (m == 1) KVb[(size_t)row * 256 + c] = f2bf(acc[r]);
          else             KVb[(size_t)row * 256 + 128 + c] = f2bf(acc[r]);
        }
      }
    }
  }
}

// ---- parallel scan: cnt[0..N) -> offs (exclusive), offs[N] = total ----
static __device__ __forceinline__ int wave_incl_scan(int v, int lane) {
#pragma unroll
  for (int d = 1; d < 64; d <<= 1) {
    int u = __shfl_up(v, d);
    if (lane >= d) v += u;
  }
  return v;
}

static __device__ __forceinline__ int block_excl_scan(int v, int* tot) {
  __shared__ int wsum[5];
  int lane = threadIdx.x & 63, wid = threadIdx.x >> 6;
  int incl = wave_incl_scan(v, lane);
  if (lane == 63) wsum[wid] = incl;
  __syncthreads();
  if (threadIdx.x == 0) {
    int a = 0;
#pragma unroll
    for (int w = 0; w < 4; w++) { int t = wsum[w]; wsum[w] = a; a += t; }
    wsum[4] = a;
  }
  __syncthreads();
  *tot = wsum[4];
  return incl - v + wsum[wid];
}

__global__ __launch_bounds__(256) void scan_sums_kernel(
    const int* __restrict__ cnt, int* __restrict__ bsum, int N) {
  int i = blockIdx.x * 256 + threadIdx.x;
  int v = (i < N) ? cnt[i] : 0;
  int tot;
  block_excl_scan(v, &tot);
  if (threadIdx.x == 0) bsum[blockIdx.x] = tot;
}

__global__ __launch_bounds__(256) void scan_tops_kernel(
    const int* __restrict__ bsum, int* __restrict__ bpre, int* __restrict__ offs,
    int NB, int N) {
  int t = threadIdx.x;
  int v = (t < NB) ? bsum[t] : 0;
  int tot;
  int ex = block_excl_scan(v, &tot);
  if (t < NB) bpre[t] = ex;
  if (t == 0) offs[N] = tot;
}

__global__ __launch_bounds__(256) void scan_final_kernel(
    const int* __restrict__ cnt, const int* __restrict__ bpre,
    int* __restrict__ offs, int N) {
  int i = blockIdx.x * 256 + threadIdx.x;
  int v = (i < N) ? cnt[i] : 0;
  int tot;
  int ex = block_excl_scan(v, &tot);
  if (i < N) offs[i] = bpre[blockIdx.x] + ex;
}

__global__ void fill_kernel(const int* __restrict__ ei, const float* __restrict__ ew,
                            const int* __restrict__ offs, const int* __restrict__ rank,
                            int2* __restrict__ recs, int E) {
  int e = blockIdx.x * blockDim.x + threadIdx.x;
  if (e < E) {
    int s = ei[e];
    int pos = offs[s] + rank[e];
    recs[pos] = make_int2(ei[E + e], __float_as_int(ew[e]));
  }
}

// Lane-per-(node,head): 8 lanes per node, lane owns one head's 16 dims.
// Batch-4 edges: all K/V loads for the batch issued independently (MLP~16).
__global__ __launch_bounds__(256) void edge_attn_kernel(
    const float* __restrict__ Qf, const ushort* __restrict__ KVb,
    const int2* __restrict__ recs, const float* __restrict__ We,
    const int* __restrict__ offs, ushort* __restrict__ AGGb, int N) {
  int t = threadIdx.x;
  int g = t >> 3;                 // node sub-index (0..31)
  int h = t & 7;                  // head
  int n = blockIdx.x * 32 + g;
  if (n >= N) return;

  float q[16];
  const float* qp = Qf + (size_t)n * 128 + h * 16;
  *(float4*)(q + 0)  = *(const float4*)(qp + 0);
  *(float4*)(q + 4)  = *(const float4*)(qp + 4);
  *(float4*)(q + 8)  = *(const float4*)(qp + 8);
  *(float4*)(q + 12) = *(const float4*)(qp + 12);
  float weh = We[h];
  int o0 = offs[n], o1 = offs[n + 1];

  float m = -INFINITY, de = 0.f;
  float acc[16];
#pragma unroll
  for (int d = 0; d < 16; d++) acc[d] = 0.f;

  unsigned hoff = (unsigned)(h << 4);
  for (int i = o0; i < o1; i += 4) {
    int2 rec[4];
#pragma unroll
    for (int u = 0; u < 4; u++) {
      int idx = (i + u < o1) ? i + u : o1 - 1;
      rec[u] = recs[idx];
    }
    const ushort* kv[4];
    uint4 k0[4], k1[4], v0[4], v1[4];
#pragma unroll
    for (int u = 0; u < 4; u++) kv[u] = KVb + (((unsigned)rec[u].x << 8) + hoff);
#pragma unroll
    for (int u = 0; u < 4; u++) { k0[u] = *(const uint4*)kv[u]; k1[u] = *(const uint4*)(kv[u] + 8); }
#pragma unroll
    for (int u = 0; u < 4; u++) { v0[u] = *(const uint4*)(kv[u] + 128); v1[u] = *(const uint4*)(kv[u] + 136); }

    float s[4];
#pragma unroll
    for (int u = 0; u < 4; u++) {
      float sv;
      sv  = q[0]  * bflo(k0[u].x) + q[1]  * bfhi(k0[u].x);
      sv += q[2]  * bflo(k0[u].y) + q[3]  * bfhi(k0[u].y);
      sv += q[4]  * bflo(k0[u].z) + q[5]  * bfhi(k0[u].z);
      sv += q[6]  * bflo(k0[u].w) + q[7]  * bfhi(k0[u].w);
      sv += q[8]  * bflo(k1[u].x) + q[9]  * bfhi(k1[u].x);
      sv += q[10] * bflo(k1[u].y) + q[11] * bfhi(k1[u].y);
      sv += q[12] * bflo(k1[u].z) + q[13] * bfhi(k1[u].z);
      sv += q[14] * bflo(k1[u].w) + q[15] * bfhi(k1[u].w);
      sv = sv * 0.25f + __int_as_float(rec[u].y) * weh;
      s[u] = (i + u < o1) ? sv : -INFINITY;
    }

#pragma unroll
    for (int u = 0; u < 4; u++) {
      float p;
      if (s[u] > m + 8.f) {                  // rescale path (rare)
        float c = __expf(m - s[u]);          // exp(-inf)=0 on first edge
        de *= c;
#pragma unroll
        for (int d = 0; d < 16; d++) acc[d] *= c;
        m = s[u];
        p = 1.f;
      } else {
        p = __expf(s[u] - m);                // bounded by e^8
      }
      de += p;
      acc[0]  += p * bflo(v0[u].x); acc[1]  += p * bfhi(v0[u].x);
      acc[2]  += p * bflo(v0[u].y); acc[3]  += p * bfhi(v0[u].y);
      acc[4]  += p * bflo(v0[u].z); acc[5]  += p * bfhi(v0[u].z);
      acc[6]  += p * bflo(v0[u].w); acc[7]  += p * bfhi(v0[u].w);
      acc[8]  += p * bflo(v1[u].x); acc[9]  += p * bfhi(v1[u].x);
      acc[10] += p * bflo(v1[u].y); acc[11] += p * bfhi(v1[u].y);
      acc[12] += p * bflo(v1[u].z); acc[13] += p * bfhi(v1[u].z);
      acc[14] += p * bflo(v1[u].w); acc[15] += p * bfhi(v1[u].w);
    }
  }

  float inv = (de > 0.f) ? 1.0f / de : 0.f;
  unsigned o[8];
#pragma unroll
  for (int j = 0; j < 8; j++) {
    ushort lo = f2bf(acc[2 * j] * inv);
    ushort hi = f2bf(acc[2 * j + 1] * inv);
    o[j] = (unsigned)lo | ((unsigned)hi << 16);
  }
  ushort* op = AGGb + (size_t)n * 128 + h * 16;
  *(uint4*)(op + 0) = make_uint4(o[0], o[1], o[2], o[3]);
  *(uint4*)(op + 8) = make_uint4(o[4], o[5], o[6], o[7]);
}

// Wo GEMM (bf16 MFMA) + residual + LayerNorm fused. Wave = 16 rows x 128 cols.
__global__ __launch_bounds__(256) void wo_ln_kernel(
    const ushort* __restrict__ AGGb, const ushort* __restrict__ Wob,
    const float* __restrict__ x, const float* __restrict__ gamma,
    const float* __restrict__ beta, float* __restrict__ out, int N) {
  int w = threadIdx.x >> 6, l = threadIdx.x & 63;
  int n0 = blockIdx.x * 64 + w * 16;
  int lr = l & 15, lg = l >> 4;
  short8 a[4];
  const ushort* arow = AGGb + (size_t)(n0 + lr) * 128 + 8 * lg;
#pragma unroll
  for (int ks = 0; ks < 4; ks++) a[ks] = *(const short8*)(arow + 32 * ks);

  f32x4 acc[8];
#pragma unroll
  for (int ct = 0; ct < 8; ct++) {
    acc[ct] = (f32x4){0.f, 0.f, 0.f, 0.f};
    const ushort* wrow = Wob + (size_t)(ct * 16 + lr) * 128 + 8 * lg;
#pragma unroll
    for (int ks = 0; ks < 4; ks++) {
      short8 b = *(const short8*)(wrow + 32 * ks);
      acc[ct] = __builtin_amdgcn_mfma_f32_16x16x32_bf16(a[ks], b, acc[ct], 0, 0, 0);
    }
  }
  float g[8], bt[8];
#pragma unroll
  for (int ct = 0; ct < 8; ct++) { g[ct] = gamma[ct * 16 + lr]; bt[ct] = beta[ct * 16 + lr]; }

#pragma unroll
  for (int r = 0; r < 4; r++) {
    int row = n0 + 4 * lg + r;
    bool ok = row < N;
    float v[8], s = 0.f, s2 = 0.f;
#pragma unroll
    for (int ct = 0; ct < 8; ct++) {
      float xv = ok ? x[(size_t)row * 128 + ct * 16 + lr] : 0.f;
      v[ct] = acc[ct][r] + xv;
      s += v[ct]; s2 += v[ct] * v[ct];
    }
#pragma unroll
    for (int d = 1; d < 16; d <<= 1) { s += __shfl_xor(s, d); s2 += __shfl_xor(s2, d); }
    float mu = s * (1.f / 128.f);
    float var = s2 * (1.f / 128.f) - mu * mu;
    float rs = rsqrtf(var + 1e-5f);
    if (ok) {
#pragma unroll
      for (int ct = 0; ct < 8; ct++)
        out[(size_t)row * 128 + ct * 16 + lr] = (v[ct] - mu) * rs * g[ct] + bt[ct];
    }
  }
}

extern "C" void kernel_launch(void* const* d_in, const int* in_sizes, int n_in,
                              void* d_out, int out_size, void* d_ws, size_t ws_size,
                              hipStream_t stream) {
  const float* x     = (const float*)d_in[0];
  const int*   ei    = (const int*)d_in[1];
  const float* ew    = (const float*)d_in[2];
  const float* Wq    = (const float*)d_in[3];
  const float* Wk    = (const float*)d_in[4];
  const float* Wv    = (const float*)d_in[5];
  const float* We    = (const float*)d_in[6];
  const float* Wo    = (const float*)d_in[7];
  const float* gamma = (const float*)d_in[8];
  const float* beta  = (const float*)d_in[9];

  int N = in_sizes[0] / 128;
  int E = in_sizes[1] / 2;
  int Npad = (N + 63) & ~63;
  int NB = (N + 255) / 256;
  int QB = Npad / 64;
  int EB = (E + 255) / 256;

  char* ws = (char*)d_ws;
  ushort* Wb   = (ushort*)ws; ws += 4 * 16384 * 2;          // [Wq,Wk,Wv,Wo] bf16
  float*  Qf   = (float*)ws;  ws += (size_t)Npad * 128 * 4;
  ushort* KVb  = (ushort*)ws; ws += (size_t)Npad * 256 * 2; // [K row | V row]
  ushort* AGGb = (ushort*)ws; ws += (size_t)Npad * 128 * 2;
  int* cnt  = (int*)ws; ws += (size_t)N * 4;
  int* offs = (int*)ws; ws += (size_t)(N + 1) * 4;
  int* rank = (int*)ws; ws += (size_t)E * 4;
  int2* recs = (int2*)ws; ws += (size_t)E * 8;
  int* bsum = (int*)ws; ws += 256 * 4;
  int* bpre = (int*)ws; ws += 256 * 4;
  ushort* Wob = Wb + 3 * 16384;

  int prep_threads = 16384 + (N + 3) / 4;
  prep_kernel<<<(prep_threads + 255) / 256, 256, 0, stream>>>(Wq, Wk, Wv, Wo, Wb, cnt, N);

  qkv_hist_kernel<<<QB + EB, 256, 0, stream>>>(x, Wb, Qf, KVb, ei, cnt, rank, N, E, QB);

  scan_sums_kernel<<<NB, 256, 0, stream>>>(cnt, bsum, N);
  scan_tops_kernel<<<1, 256, 0, stream>>>(bsum, bpre, offs, NB, N);
  scan_final_kernel<<<NB, 256, 0, stream>>>(cnt, bpre, offs, N);
  fill_kernel<<<EB, 256, 0, stream>>>(ei, ew, offs, rank, recs, E);

  edge_attn_kernel<<<(N + 31) / 32, 256, 0, stream>>>(Qf, KVb, recs, We, offs, AGGb, N);

  wo_ln_kernel<<<Npad / 64, 256, 0, stream>>>(AGGb, Wob, x, gamma, beta, (float*)d_out, N);
}